// Round 1
// 148.824 us; speedup vs baseline: 1.3759x; 1.3759x over previous
//
#include <hip/hip_runtime.h>
#include <stdint.h>

#define BB 4
#define NN 4096
#define MM 16
#define KNN 5
#define NSAMP 100

// workspace float-index layout
#define WS_CONS 0      // 64 floats: per-block cons partial sums (was 4096)
#define WS_VEL  4096   // 64
#define WS_BSUM 4160   // 64
#define WS_BCNT 4224   // 64
#define WS_OPEN 4288   // 64 (obstacle pen sums per (b,m))
#define WS_OCNT 4352   // 64 (obstacle near counts per (b,m))
#define WS_IDX  4416   // 400 ints (100 samples x 4 indices)

#define CELLH 0.0625f  // 1/16

// ---------------- threefry2x32 (bit-exact JAX) ----------------
__device__ __forceinline__ void tf2x32(uint32_t k0, uint32_t k1,
                                       uint32_t c0, uint32_t c1,
                                       uint32_t& o0, uint32_t& o1) {
  const uint32_t ks2 = k0 ^ k1 ^ 0x1BD11BDAu;
  uint32_t x0 = c0 + k0, x1 = c1 + k1;
#define TF_RND(r) { x0 += x1; x1 = (x1 << (r)) | (x1 >> (32 - (r))); x1 ^= x0; }
  TF_RND(13) TF_RND(15) TF_RND(26) TF_RND(6)
  x0 += k1;  x1 += ks2 + 1u;
  TF_RND(17) TF_RND(29) TF_RND(16) TF_RND(24)
  x0 += ks2; x1 += k0 + 2u;
  TF_RND(13) TF_RND(15) TF_RND(26) TF_RND(6)
  x0 += k0;  x1 += k1 + 3u;
  TF_RND(17) TF_RND(29) TF_RND(16) TF_RND(24)
  x0 += k1;  x1 += ks2 + 4u;
  TF_RND(13) TF_RND(15) TF_RND(26) TF_RND(6)
  x0 += ks2; x1 += k0 + 5u;
#undef TF_RND
  o0 = x0; o1 = x1;
}

__device__ __forceinline__ float blockReduce256(float v, float* red) {
  int t = threadIdx.x;
  red[t] = v;
  __syncthreads();
#pragma unroll
  for (int off = 128; off > 0; off >>= 1) {
    if (t < off) red[t] += red[t + off];
    __syncthreads();
  }
  float r = red[0];
  __syncthreads();
  return r;
}

// ---------------- vel-MSE + boundary loss partials ----------------
__global__ __launch_bounds__(256) void k_velbnd(const float2* __restrict__ pred,
                                                const float2* __restrict__ targ,
                                                const float2* __restrict__ pos,
                                                float* __restrict__ ws) {
  __shared__ float red[256];
  int tid = blockIdx.x * 256 + threadIdx.x;   // exactly B*N = 16384 threads
  float2 p = pred[tid], tg = targ[tid], ps = pos[tid];
  float ex = p.x - tg.x, ey = p.y - tg.y;
  float velsq = ex * ex + ey * ey;

  float x = ps.x, y = ps.y;
  bool mask = (x < 0.05f) || (x > 0.95f) || (y < 0.05f) || (y > 0.95f);
  // argmin of [x, 1-x, y, 1-y], first occurrence
  float m0 = x, m1 = 1.0f - x, m2 = y, m3 = 1.0f - y;
  int bt = 0; float mv = m0;
  if (m1 < mv) { mv = m1; bt = 1; }
  if (m2 < mv) { mv = m2; bt = 2; }
  if (m3 < mv) { mv = m3; bt = 3; }
  float nx = (bt == 0) ? -1.0f : (bt == 1 ? 1.0f : 0.0f);
  float ny = (bt == 2) ? -1.0f : (bt == 3 ? 1.0f : 0.0f);
  float nc = p.x * nx + p.y * ny;
  float bs = mask ? nc * nc : 0.0f;
  float bc = mask ? 1.0f : 0.0f;

  float v1 = blockReduce256(velsq, red);
  float v2 = blockReduce256(bs, red);
  float v3 = blockReduce256(bc, red);
  if (threadIdx.x == 0) {
    ws[WS_VEL + blockIdx.x] = v1;
    ws[WS_BSUM + blockIdx.x] = v2;
    ws[WS_BCNT + blockIdx.x] = v3;
  }
}

// ---------------- consistency loss: grid-hash exact kNN ----------------
// 16x16 uniform grid over [0,1)^2, per-block in-LDS count-sort of the batch,
// one query point per thread (in cell-sorted order for wave coherence).
// Ring expansion with conservative bound guarantees the candidate set is a
// superset of the reference top-5; selection key (dist_bits<<32 | j) and the
// distance expression are IDENTICAL to the verified brute-force kernel.
__global__ __launch_bounds__(256) void k_cons(const float2* __restrict__ pos,
                                              const float2* __restrict__ vel,
                                              float* __restrict__ partial) {
  __shared__ float2 spos[NN];        // 32 KiB, cell-sorted positions
  __shared__ int    sidx[NN];        // 16 KiB, original indices
  __shared__ int    cellstart[257];
  __shared__ int    ccur[256];
  __shared__ float  red[256];

  int b = blockIdx.x >> 4;           // 16 blocks per batch
  int tid = threadIdx.x;

  // ---- histogram ----
  ccur[tid] = 0;
  __syncthreads();
  float2 mypts[16];
  int mycell[16];
#pragma unroll
  for (int r = 0; r < 16; ++r) {
    float2 p = pos[b * NN + r * 256 + tid];
    mypts[r] = p;
    int cx = (int)(p.x * 16.0f); cx = cx > 15 ? 15 : cx;
    int cy = (int)(p.y * 16.0f); cy = cy > 15 ? 15 : cy;
    int c = cx * 16 + cy;
    mycell[r] = c;
    atomicAdd(&ccur[c], 1);
  }
  __syncthreads();

  // ---- exclusive scan (Hillis-Steele over 257 entries, entry 0 = 0) ----
  if (tid == 0) cellstart[0] = 0;
  cellstart[tid + 1] = ccur[tid];
  __syncthreads();
#pragma unroll
  for (int off = 1; off < 256; off <<= 1) {
    int i = tid + 1;
    int v = (i >= off) ? cellstart[i - off] : 0;
    __syncthreads();
    if (i >= off) cellstart[i] += v;
    __syncthreads();
  }
  ccur[tid] = cellstart[tid];        // scatter cursors
  __syncthreads();

  // ---- scatter (intra-cell order arbitrary; selection is key-based) ----
#pragma unroll
  for (int r = 0; r < 16; ++r) {
    int slot = atomicAdd(&ccur[mycell[r]], 1);
    spos[slot] = mypts[r];
    sidx[slot] = r * 256 + tid;
  }
  __syncthreads();

  // ---- query: one sorted point per thread ----
  int q = ((blockIdx.x & 15) << 8) + tid;
  float2 pi = spos[q];
  int iorig = sidx[q];
  float sqi = pi.x * pi.x + pi.y * pi.y;
  int cx = (int)(pi.x * 16.0f); cx = cx > 15 ? 15 : cx;
  int cy = (int)(pi.y * 16.0f); cy = cy > 15 ? 15 : cy;

  unsigned long long b0 = ~0ull, b1 = ~0ull, b2 = ~0ull, b3 = ~0ull, b4 = ~0ull;

  auto scanSpan = [&](int s0, int s1) {
    for (int s = s0; s < s1; ++s) {
      float2 pj = spos[s];
      int jn = sidx[s];
      if (jn == iorig) continue;                 // self-exclusion
      float sqj = pj.x * pj.x + pj.y * pj.y;
      float dt = pi.x * pj.x + pi.y * pj.y;
      float d2 = sqi + sqj - 2.0f * dt;          // reference formula, verbatim
      float dist = sqrtf(fmaxf(d2, 0.0f));
      unsigned long long key =
          ((unsigned long long)__float_as_uint(dist) << 32) | (unsigned)jn;
      if (key < b4) {
        b4 = key;
        if (b4 < b3) { unsigned long long t2 = b4; b4 = b3; b3 = t2; }
        if (b3 < b2) { unsigned long long t2 = b3; b3 = b2; b2 = t2; }
        if (b2 < b1) { unsigned long long t2 = b2; b2 = b1; b1 = t2; }
        if (b1 < b0) { unsigned long long t2 = b1; b1 = b0; b0 = t2; }
      }
    }
  };

  int R = 0;
  while (true) {
    int xlo = cx - R; if (xlo < 0) xlo = 0;
    int xhi = cx + R; if (xhi > 15) xhi = 15;
    int ylo = cy - R; if (ylo < 0) ylo = 0;
    int yhi = cy + R; if (yhi > 15) yhi = 15;
    // scan ring R (cells at Chebyshev distance exactly R, clamped to grid)
    for (int gx = xlo; gx <= xhi; ++gx) {
      if (R == 0 || gx == cx - R || gx == cx + R) {
        // full column span [ylo, yhi] — contiguous in sorted order
        scanSpan(cellstart[(gx << 4) + ylo], cellstart[(gx << 4) + yhi + 1]);
      } else {
        if (cy - R >= 0)
          scanSpan(cellstart[(gx << 4) + cy - R], cellstart[(gx << 4) + cy - R + 1]);
        if (cy + R <= 15)
          scanSpan(cellstart[(gx << 4) + cy + R], cellstart[(gx << 4) + cy + R + 1]);
      }
    }
    bool full = (xlo == 0) && (xhi == 15) && (ylo == 0) && (yhi == 15);
    if (full) break;                             // whole grid searched
    if (b4 != ~0ull) {
      // computed dist of 5th-best; compare against min geometric distance
      // to any unsearched point. 1e-3 margin >> ~1e-5 float error of the
      // cancellation-prone d2 formula -> guaranteed superset of true top-5.
      float dist5 = __uint_as_float((uint32_t)(b4 >> 32));
      float dout = 1e30f;
      if (xlo > 0)  dout = fminf(dout, pi.x - (float)xlo * CELLH);
      if (xhi < 15) dout = fminf(dout, (float)(xhi + 1) * CELLH - pi.x);
      if (ylo > 0)  dout = fminf(dout, pi.y - (float)ylo * CELLH);
      if (yhi < 15) dout = fminf(dout, (float)(yhi + 1) * CELLH - pi.y);
      if (dist5 + 1e-3f <= dout) break;
    }
    ++R;
  }

  float2 vi = vel[b * NN + iorig];
  float acc = 0.0f;
  auto addnb = [&](unsigned long long m) {       // increasing-dist order (as before)
    unsigned jn = (unsigned)(m & 0xFFFFFFFFull);
    float dn = __uint_as_float((uint32_t)(m >> 32));
    float2 vj = vel[b * NN + jn];
    float dvx = vi.x - vj.x, dvy = vi.y - vj.y;
    float vd = sqrtf(dvx * dvx + dvy * dvy);
    float w = 1.0f / (dn + 1e-6f);
    acc += vd * w;
  };
  addnb(b0); addnb(b1); addnb(b2); addnb(b3); addnb(b4);

  float tot = blockReduce256(acc, red);
  if (tid == 0) partial[blockIdx.x] = tot;
}

// ---------------- obstacle loss: one wave per (b, m) ----------------
__global__ __launch_bounds__(64) void k_obs(const float2* __restrict__ pos,
                                            const float2* __restrict__ vel,
                                            const float* __restrict__ obst,
                                            float* __restrict__ ws) {
  int blk = blockIdx.x;        // b*16 + m
  int b = blk >> 4;
  int lane = threadIdx.x;
  float cx = obst[blk * 3 + 0], cy = obst[blk * 3 + 1], r = obst[blk * 3 + 2];
  float pensum = 0.0f, cnt = 0.0f;
  for (int it = 0; it < NN / 64; ++it) {
    int n = (it << 6) | lane;
    float2 ps = pos[b * NN + n];
    float2 v = vel[b * NN + n];
    float dx = ps.x - cx, dy = ps.y - cy;
    float d = sqrtf(dx * dx + dy * dy);
    bool near = d < r * 2.0f;
    float dpe = d + 1e-6f;
    float dirx = dx / dpe, diry = dy / dpe;
    float w = expf(-(d - r) / (r * 0.5f));
    float proj = v.x * dirx + v.y * diry;
    float npj = fmaxf(-proj, 0.0f);
    float pp = w * npj * npj;
    if (near) { pensum += pp; cnt += 1.0f; }
  }
#pragma unroll
  for (int off = 32; off >= 1; off >>= 1) {
    pensum += __shfl_xor(pensum, off, 64);
    cnt += __shfl_xor(cnt, off, 64);
  }
  if (lane == 0) { ws[WS_OPEN + blk] = pensum; ws[WS_OCNT + blk] = cnt; }
}

// ---------------- JAX permutation indices (threefry_partitionable=True) ----
__global__ __launch_bounds__(256) void k_idx(int* __restrict__ out_idx) {
  __shared__ unsigned long long keys[NN];        // 32 KiB
  __shared__ unsigned long long red64[256];      // 2 KiB
  __shared__ unsigned long long bucketbuf[256];  // 2 KiB
  __shared__ int hist[257];
  __shared__ uint32_t ksh[4];
  __shared__ int ptarget[4];
  __shared__ int bksel, bbase, bcnt;
  int s = blockIdx.x;
  int tid = threadIdx.x;

  if (tid == 0) {
    uint32_t K0, K1;                     // keys[s] = tf(base, (0, s))
    tf2x32(0u, 42u, 0u, (uint32_t)s, K0, K1);
    uint32_t A0, A1, s10, s11, s20, s21;
    tf2x32(K0, K1, 0u, 0u, A0, A1);      // carried key after split #1
    tf2x32(K0, K1, 0u, 1u, s10, s11);    // subkey round 1
    tf2x32(A0, A1, 0u, 1u, s20, s21);    // subkey round 2 (from carried key)
    ksh[0] = s10; ksh[1] = s11;
    ksh[2] = s20; ksh[3] = s21;
  }
  __syncthreads();

  // ---- round-2 keys; find positions of the 4 smallest ----
  {
    uint32_t sk0 = ksh[2], sk1 = ksh[3];
    for (int i = tid; i < NN; i += 256) {
      uint32_t r0, r1;
      tf2x32(sk0, sk1, 0u, (uint32_t)i, r0, r1);
      keys[i] = ((unsigned long long)(r0 ^ r1) << 32) | (unsigned)i;
    }
  }
  __syncthreads();
  for (int t = 0; t < 4; ++t) {
    unsigned long long local = ~0ull;
    for (int i = tid; i < NN; i += 256) {
      unsigned long long k = keys[i];
      local = (k < local) ? k : local;
    }
    red64[tid] = local;
    __syncthreads();
#pragma unroll
    for (int off = 128; off > 0; off >>= 1) {
      if (tid < off) {
        unsigned long long o = red64[tid + off];
        if (o < red64[tid]) red64[tid] = o;
      }
      __syncthreads();
    }
    if (tid == 0) {
      unsigned long long m = red64[0];
      int p = (int)(m & 0xFFFFFFFFull);
      ptarget[t] = p;
      keys[p] = ~0ull;                   // exclude for next round
    }
    __syncthreads();
  }

  // ---- round-1 keys + top-byte histogram ----
  if (tid < 257) hist[tid] = 0;
  if (tid == 0) hist[256] = 0;
  __syncthreads();
  {
    uint32_t sk0 = ksh[0], sk1 = ksh[1];
    for (int i = tid; i < NN; i += 256) {
      uint32_t r0, r1;
      tf2x32(sk0, sk1, 0u, (uint32_t)i, r0, r1);
      unsigned long long k = ((unsigned long long)(r0 ^ r1) << 32) | (unsigned)i;
      keys[i] = k;
      atomicAdd(&hist[(int)(k >> 56)], 1);
    }
  }
  __syncthreads();
  if (tid == 0) {                        // exclusive prefix sum, 256 bins
    int run = 0;
    for (int b2 = 0; b2 < 256; ++b2) { int c = hist[b2]; hist[b2] = run; run += c; }
    hist[256] = run;                     // == NN
  }
  __syncthreads();

  // ---- rank-select perm1[p_t] for each of the 4 targets ----
  for (int t = 0; t < 4; ++t) {
    if (tid == 0) {
      int p = ptarget[t];
      int lo = 0, hi = 255;              // largest b with hist[b] <= p
      while (lo < hi) {
        int mid = (lo + hi + 1) >> 1;
        if (hist[mid] <= p) lo = mid; else hi = mid - 1;
      }
      bksel = lo; bbase = hist[lo]; bcnt = 0;
    }
    __syncthreads();
    int bk = bksel;
    for (int i = tid; i < NN; i += 256) {
      unsigned long long k = keys[i];
      if ((int)(k >> 56) == bk) {
        int slot = atomicAdd(&bcnt, 1);
        if (slot < 256) bucketbuf[slot] = k;
      }
    }
    __syncthreads();
    if (tid == 0) {
      int c = bcnt; if (c > 256) c = 256;
      int r = ptarget[t] - bbase;        // rank within bucket
      for (int a2 = 1; a2 < c; ++a2) {   // insertion sort (c ~ 16)
        unsigned long long v = bucketbuf[a2];
        int b3 = a2 - 1;
        while (b3 >= 0 && bucketbuf[b3] > v) { bucketbuf[b3 + 1] = bucketbuf[b3]; --b3; }
        bucketbuf[b3 + 1] = v;
      }
      out_idx[s * 4 + t] = (int)(bucketbuf[r] & 0xFFFFFFFFull);
    }
    __syncthreads();
  }
}

// ---------------- final combine ----------------
__global__ __launch_bounds__(256) void k_final(const float* __restrict__ ws,
                                               const int* __restrict__ idxbuf,
                                               const float2* __restrict__ pos,
                                               const float2* __restrict__ vel,
                                               float* __restrict__ out) {
  __shared__ float red[256];
  int t = threadIdx.x;
  float acc;

  acc = 0.0f;
  for (int q = t; q < 64; q += 256) acc += ws[WS_CONS + q];   // 64 partials now
  float consS = blockReduce256(acc, red);

  acc = 0.0f;
  for (int q = t; q < 64; q += 256) acc += ws[WS_VEL + q];
  float velS = blockReduce256(acc, red);

  acc = 0.0f;
  for (int q = t; q < 64; q += 256) acc += ws[WS_BSUM + q];
  float bsumS = blockReduce256(acc, red);

  acc = 0.0f;
  for (int q = t; q < 64; q += 256) acc += ws[WS_BCNT + q];
  float bcntS = blockReduce256(acc, red);

  acc = 0.0f;
  for (int q = t; q < 64; q += 256) {
    float psum = ws[WS_OPEN + q], c = ws[WS_OCNT + q];
    acc += (c > 0.0f) ? psum / fmaxf(c, 1.0f) : 0.0f;
  }
  float obsS = blockReduce256(acc, red);

  acc = 0.0f;
  for (int q = t; q < BB * NSAMP; q += 256) {
    int b = q / NSAMP, s = q % NSAMP;
    int i0 = idxbuf[s * 4 + 0], i1 = idxbuf[s * 4 + 1], i2 = idxbuf[s * 4 + 2];
    float2 p0 = pos[b * NN + i0], p1 = pos[b * NN + i1], p2 = pos[b * NN + i2];
    float2 v0 = vel[b * NN + i0], v1 = vel[b * NN + i1], v2 = vel[b * NN + i2];
    float dx = p1.x - p0.x, dy = p2.y - p0.y;
    float dvx = (v1.x - v0.x) / (dx + 1e-6f);
    float dvy = (v2.y - v0.y) / (dy + 1e-6f);
    float sm = dvx + dvy;
    acc += sm * sm;
  }
  float divS = blockReduce256(acc, red);

  if (t == 0) {
    float vel_loss = velS / (float)(BB * NN * 2);
    float cons = consS / (float)(BB * NN * KNN);
    float bnd = (bcntS > 0.0f) ? bsumS / fmaxf(bcntS, 1.0f) : 0.0f;
    float obs = obsS / (float)(BB * MM);
    float dv = divS / (float)(BB * NSAMP);
    out[0] = 1.0f * vel_loss + 0.1f * cons + 0.5f * bnd + 1.0f * obs + 0.1f * dv;
  }
}

extern "C" void kernel_launch(void* const* d_in, const int* in_sizes, int n_in,
                              void* d_out, int out_size, void* d_ws, size_t ws_size,
                              hipStream_t stream) {
  (void)in_sizes; (void)n_in; (void)out_size; (void)ws_size;
  const float2* pred = (const float2*)d_in[0];
  const float2* targ = (const float2*)d_in[1];
  const float2* pos  = (const float2*)d_in[2];
  const float*  obst = (const float*)d_in[3];
  float* ws = (float*)d_ws;
  int* idxbuf = ((int*)d_ws) + WS_IDX;
  float* out = (float*)d_out;

  hipLaunchKernelGGL(k_velbnd, dim3(64), dim3(256), 0, stream, pred, targ, pos, ws);
  hipLaunchKernelGGL(k_cons, dim3(64), dim3(256), 0, stream, pos, pred, ws + WS_CONS);
  hipLaunchKernelGGL(k_obs, dim3(BB * MM), dim3(64), 0, stream, pos, pred, obst, ws);
  hipLaunchKernelGGL(k_idx, dim3(NSAMP), dim3(256), 0, stream, idxbuf);
  hipLaunchKernelGGL(k_final, dim3(1), dim3(256), 0, stream, ws, idxbuf, pos, pred, out);
}

// Round 2
// 85.432 us; speedup vs baseline: 2.3969x; 1.7420x over previous
//
#include <hip/hip_runtime.h>
#include <stdint.h>
#include <algorithm>
#include <mutex>

#define BB 4
#define NN 4096
#define MM 16
#define KNN 5
#define NSAMP 100

// workspace float-index layout
#define WS_CONS 0      // 64 floats: per-block cons partial sums
#define WS_VEL  4096   // 64
#define WS_BSUM 4160   // 64
#define WS_BCNT 4224   // 64
#define WS_OPEN 4288   // 64 (obstacle pen sums per (b,m))
#define WS_OCNT 4352   // 64 (obstacle near counts per (b,m))
#define WS_IDX  4416   // 400 ints (100 samples x 4 indices)

#define CELLH 0.0625f  // 1/16

// ---------------- threefry2x32 (bit-exact JAX) ----------------
__host__ __device__ __forceinline__ void tf2x32(uint32_t k0, uint32_t k1,
                                                uint32_t c0, uint32_t c1,
                                                uint32_t& o0, uint32_t& o1) {
  const uint32_t ks2 = k0 ^ k1 ^ 0x1BD11BDAu;
  uint32_t x0 = c0 + k0, x1 = c1 + k1;
#define TF_RND(r) { x0 += x1; x1 = (x1 << (r)) | (x1 >> (32 - (r))); x1 ^= x0; }
  TF_RND(13) TF_RND(15) TF_RND(26) TF_RND(6)
  x0 += k1;  x1 += ks2 + 1u;
  TF_RND(17) TF_RND(29) TF_RND(16) TF_RND(24)
  x0 += ks2; x1 += k0 + 2u;
  TF_RND(13) TF_RND(15) TF_RND(26) TF_RND(6)
  x0 += k0;  x1 += k1 + 3u;
  TF_RND(17) TF_RND(29) TF_RND(16) TF_RND(24)
  x0 += k1;  x1 += ks2 + 4u;
  TF_RND(13) TF_RND(15) TF_RND(26) TF_RND(6)
  x0 += ks2; x1 += k0 + 5u;
#undef TF_RND
  o0 = x0; o1 = x1;
}

__device__ __forceinline__ float blockReduce256(float v, float* red) {
  int t = threadIdx.x;
  red[t] = v;
  __syncthreads();
#pragma unroll
  for (int off = 128; off > 0; off >>= 1) {
    if (t < off) red[t] += red[t + off];
    __syncthreads();
  }
  float r = red[0];
  __syncthreads();
  return r;
}

// ---------------- vel-MSE + boundary loss partials ----------------
__global__ __launch_bounds__(256) void k_velbnd(const float2* __restrict__ pred,
                                                const float2* __restrict__ targ,
                                                const float2* __restrict__ pos,
                                                float* __restrict__ ws) {
  __shared__ float red[256];
  int tid = blockIdx.x * 256 + threadIdx.x;   // exactly B*N = 16384 threads
  float2 p = pred[tid], tg = targ[tid], ps = pos[tid];
  float ex = p.x - tg.x, ey = p.y - tg.y;
  float velsq = ex * ex + ey * ey;

  float x = ps.x, y = ps.y;
  bool mask = (x < 0.05f) || (x > 0.95f) || (y < 0.05f) || (y > 0.95f);
  // argmin of [x, 1-x, y, 1-y], first occurrence
  float m0 = x, m1 = 1.0f - x, m2 = y, m3 = 1.0f - y;
  int bt = 0; float mv = m0;
  if (m1 < mv) { mv = m1; bt = 1; }
  if (m2 < mv) { mv = m2; bt = 2; }
  if (m3 < mv) { mv = m3; bt = 3; }
  float nx = (bt == 0) ? -1.0f : (bt == 1 ? 1.0f : 0.0f);
  float ny = (bt == 2) ? -1.0f : (bt == 3 ? 1.0f : 0.0f);
  float nc = p.x * nx + p.y * ny;
  float bs = mask ? nc * nc : 0.0f;
  float bc = mask ? 1.0f : 0.0f;

  float v1 = blockReduce256(velsq, red);
  float v2 = blockReduce256(bs, red);
  float v3 = blockReduce256(bc, red);
  if (threadIdx.x == 0) {
    ws[WS_VEL + blockIdx.x] = v1;
    ws[WS_BSUM + blockIdx.x] = v2;
    ws[WS_BCNT + blockIdx.x] = v3;
  }
}

// ---------------- consistency loss: grid-hash exact kNN ----------------
// 16x16 uniform grid over [0,1)^2, per-block in-LDS count-sort of the batch,
// one query point per thread (in cell-sorted order for wave coherence).
// Ring expansion with conservative bound guarantees the candidate set is a
// superset of the reference top-5; selection key (dist_bits<<32 | j) and the
// distance expression are IDENTICAL to the verified brute-force kernel.
__global__ __launch_bounds__(256) void k_cons(const float2* __restrict__ pos,
                                              const float2* __restrict__ vel,
                                              float* __restrict__ partial) {
  __shared__ float2 spos[NN];        // 32 KiB, cell-sorted positions
  __shared__ int    sidx[NN];        // 16 KiB, original indices
  __shared__ int    cellstart[257];
  __shared__ int    ccur[256];
  __shared__ float  red[256];

  int b = blockIdx.x >> 4;           // 16 blocks per batch
  int tid = threadIdx.x;

  // ---- histogram ----
  ccur[tid] = 0;
  __syncthreads();
  float2 mypts[16];
  int mycell[16];
#pragma unroll
  for (int r = 0; r < 16; ++r) {
    float2 p = pos[b * NN + r * 256 + tid];
    mypts[r] = p;
    int cx = (int)(p.x * 16.0f); cx = cx > 15 ? 15 : cx;
    int cy = (int)(p.y * 16.0f); cy = cy > 15 ? 15 : cy;
    int c = cx * 16 + cy;
    mycell[r] = c;
    atomicAdd(&ccur[c], 1);
  }
  __syncthreads();

  // ---- exclusive scan (Hillis-Steele over 257 entries, entry 0 = 0) ----
  if (tid == 0) cellstart[0] = 0;
  cellstart[tid + 1] = ccur[tid];
  __syncthreads();
#pragma unroll
  for (int off = 1; off < 256; off <<= 1) {
    int i = tid + 1;
    int v = (i >= off) ? cellstart[i - off] : 0;
    __syncthreads();
    if (i >= off) cellstart[i] += v;
    __syncthreads();
  }
  ccur[tid] = cellstart[tid];        // scatter cursors
  __syncthreads();

  // ---- scatter (intra-cell order arbitrary; selection is key-based) ----
#pragma unroll
  for (int r = 0; r < 16; ++r) {
    int slot = atomicAdd(&ccur[mycell[r]], 1);
    spos[slot] = mypts[r];
    sidx[slot] = r * 256 + tid;
  }
  __syncthreads();

  // ---- query: one sorted point per thread ----
  int q = ((blockIdx.x & 15) << 8) + tid;
  float2 pi = spos[q];
  int iorig = sidx[q];
  float sqi = pi.x * pi.x + pi.y * pi.y;
  int cx = (int)(pi.x * 16.0f); cx = cx > 15 ? 15 : cx;
  int cy = (int)(pi.y * 16.0f); cy = cy > 15 ? 15 : cy;

  unsigned long long b0 = ~0ull, b1 = ~0ull, b2 = ~0ull, b3 = ~0ull, b4 = ~0ull;

  auto scanSpan = [&](int s0, int s1) {
    for (int s = s0; s < s1; ++s) {
      float2 pj = spos[s];
      int jn = sidx[s];
      if (jn == iorig) continue;                 // self-exclusion
      float sqj = pj.x * pj.x + pj.y * pj.y;
      float dt = pi.x * pj.x + pi.y * pj.y;
      float d2 = sqi + sqj - 2.0f * dt;          // reference formula, verbatim
      float dist = sqrtf(fmaxf(d2, 0.0f));
      unsigned long long key =
          ((unsigned long long)__float_as_uint(dist) << 32) | (unsigned)jn;
      if (key < b4) {
        b4 = key;
        if (b4 < b3) { unsigned long long t2 = b4; b4 = b3; b3 = t2; }
        if (b3 < b2) { unsigned long long t2 = b3; b3 = b2; b2 = t2; }
        if (b2 < b1) { unsigned long long t2 = b2; b2 = b1; b1 = t2; }
        if (b1 < b0) { unsigned long long t2 = b1; b1 = b0; b0 = t2; }
      }
    }
  };

  int R = 0;
  while (true) {
    int xlo = cx - R; if (xlo < 0) xlo = 0;
    int xhi = cx + R; if (xhi > 15) xhi = 15;
    int ylo = cy - R; if (ylo < 0) ylo = 0;
    int yhi = cy + R; if (yhi > 15) yhi = 15;
    // scan ring R (cells at Chebyshev distance exactly R, clamped to grid)
    for (int gx = xlo; gx <= xhi; ++gx) {
      if (R == 0 || gx == cx - R || gx == cx + R) {
        // full column span [ylo, yhi] — contiguous in sorted order
        scanSpan(cellstart[(gx << 4) + ylo], cellstart[(gx << 4) + yhi + 1]);
      } else {
        if (cy - R >= 0)
          scanSpan(cellstart[(gx << 4) + cy - R], cellstart[(gx << 4) + cy - R + 1]);
        if (cy + R <= 15)
          scanSpan(cellstart[(gx << 4) + cy + R], cellstart[(gx << 4) + cy + R + 1]);
      }
    }
    bool full = (xlo == 0) && (xhi == 15) && (ylo == 0) && (yhi == 15);
    if (full) break;                             // whole grid searched
    if (b4 != ~0ull) {
      // computed dist of 5th-best; compare against min geometric distance
      // to any unsearched point. 1e-3 margin >> ~1e-5 float error of the
      // cancellation-prone d2 formula -> guaranteed superset of true top-5.
      float dist5 = __uint_as_float((uint32_t)(b4 >> 32));
      float dout = 1e30f;
      if (xlo > 0)  dout = fminf(dout, pi.x - (float)xlo * CELLH);
      if (xhi < 15) dout = fminf(dout, (float)(xhi + 1) * CELLH - pi.x);
      if (ylo > 0)  dout = fminf(dout, pi.y - (float)ylo * CELLH);
      if (yhi < 15) dout = fminf(dout, (float)(yhi + 1) * CELLH - pi.y);
      if (dist5 + 1e-3f <= dout) break;
    }
    ++R;
  }

  float2 vi = vel[b * NN + iorig];
  float acc = 0.0f;
  auto addnb = [&](unsigned long long m) {       // increasing-dist order (as before)
    unsigned jn = (unsigned)(m & 0xFFFFFFFFull);
    float dn = __uint_as_float((uint32_t)(m >> 32));
    float2 vj = vel[b * NN + jn];
    float dvx = vi.x - vj.x, dvy = vi.y - vj.y;
    float vd = sqrtf(dvx * dvx + dvy * dvy);
    float w = 1.0f / (dn + 1e-6f);
    acc += vd * w;
  };
  addnb(b0); addnb(b1); addnb(b2); addnb(b3); addnb(b4);

  float tot = blockReduce256(acc, red);
  if (tid == 0) partial[blockIdx.x] = tot;
}

// ---------------- obstacle loss: one wave per (b, m) ----------------
__global__ __launch_bounds__(64) void k_obs(const float2* __restrict__ pos,
                                            const float2* __restrict__ vel,
                                            const float* __restrict__ obst,
                                            float* __restrict__ ws) {
  int blk = blockIdx.x;        // b*16 + m
  int b = blk >> 4;
  int lane = threadIdx.x;
  float cx = obst[blk * 3 + 0], cy = obst[blk * 3 + 1], r = obst[blk * 3 + 2];
  float pensum = 0.0f, cnt = 0.0f;
  for (int it = 0; it < NN / 64; ++it) {
    int n = (it << 6) | lane;
    float2 ps = pos[b * NN + n];
    float2 v = vel[b * NN + n];
    float dx = ps.x - cx, dy = ps.y - cy;
    float d = sqrtf(dx * dx + dy * dy);
    bool near = d < r * 2.0f;
    float dpe = d + 1e-6f;
    float dirx = dx / dpe, diry = dy / dpe;
    float w = expf(-(d - r) / (r * 0.5f));
    float proj = v.x * dirx + v.y * diry;
    float npj = fmaxf(-proj, 0.0f);
    float pp = w * npj * npj;
    if (near) { pensum += pp; cnt += 1.0f; }
  }
#pragma unroll
  for (int off = 32; off >= 1; off >>= 1) {
    pensum += __shfl_xor(pensum, off, 64);
    cnt += __shfl_xor(cnt, off, 64);
  }
  if (lane == 0) { ws[WS_OPEN + blk] = pensum; ws[WS_OCNT + blk] = cnt; }
}

// ---------------- final combine ----------------
__global__ __launch_bounds__(256) void k_final(const float* __restrict__ ws,
                                               const int* __restrict__ idxbuf,
                                               const float2* __restrict__ pos,
                                               const float2* __restrict__ vel,
                                               float* __restrict__ out) {
  __shared__ float red[256];
  int t = threadIdx.x;
  float acc;

  acc = 0.0f;
  for (int q = t; q < 64; q += 256) acc += ws[WS_CONS + q];
  float consS = blockReduce256(acc, red);

  acc = 0.0f;
  for (int q = t; q < 64; q += 256) acc += ws[WS_VEL + q];
  float velS = blockReduce256(acc, red);

  acc = 0.0f;
  for (int q = t; q < 64; q += 256) acc += ws[WS_BSUM + q];
  float bsumS = blockReduce256(acc, red);

  acc = 0.0f;
  for (int q = t; q < 64; q += 256) acc += ws[WS_BCNT + q];
  float bcntS = blockReduce256(acc, red);

  acc = 0.0f;
  for (int q = t; q < 64; q += 256) {
    float psum = ws[WS_OPEN + q], c = ws[WS_OCNT + q];
    acc += (c > 0.0f) ? psum / fmaxf(c, 1.0f) : 0.0f;
  }
  float obsS = blockReduce256(acc, red);

  acc = 0.0f;
  for (int q = t; q < BB * NSAMP; q += 256) {
    int b = q / NSAMP, s = q % NSAMP;
    int i0 = idxbuf[s * 4 + 0], i1 = idxbuf[s * 4 + 1], i2 = idxbuf[s * 4 + 2];
    float2 p0 = pos[b * NN + i0], p1 = pos[b * NN + i1], p2 = pos[b * NN + i2];
    float2 v0 = vel[b * NN + i0], v1 = vel[b * NN + i1], v2 = vel[b * NN + i2];
    float dx = p1.x - p0.x, dy = p2.y - p0.y;
    float dvx = (v1.x - v0.x) / (dx + 1e-6f);
    float dvy = (v2.y - v0.y) / (dy + 1e-6f);
    float sm = dvx + dvy;
    acc += sm * sm;
  }
  float divS = blockReduce256(acc, red);

  if (t == 0) {
    float vel_loss = velS / (float)(BB * NN * 2);
    float cons = consS / (float)(BB * NN * KNN);
    float bnd = (bcntS > 0.0f) ? bsumS / fmaxf(bcntS, 1.0f) : 0.0f;
    float obs = obsS / (float)(BB * MM);
    float dv = divS / (float)(BB * NSAMP);
    out[0] = 1.0f * vel_loss + 0.1f * cons + 0.5f * bnd + 1.0f * obs + 0.1f * dv;
  }
}

// ---------------- host-side JAX permutation indices ----------------
// k_idx's output is input-independent (fixed key 42, fixed n, fixed NSAMP):
// compute it ONCE on the host with bit-identical integer ops, then feed the
// 400 ints to the graph via a hipMemcpyAsync node (re-executed every replay,
// so workspace re-poisoning is handled).
static int  g_idx_host[NSAMP * 4];
static std::once_flag g_idx_flag;

static void compute_idx_host() {
  static unsigned long long kbuf[NN];   // round-1 keys (sorted below)
  for (int s = 0; s < NSAMP; ++s) {
    uint32_t K0, K1;                    // keys[s] = tf(base, (0, s))
    tf2x32(0u, 42u, 0u, (uint32_t)s, K0, K1);
    uint32_t A0, A1, s10, s11, s20, s21;
    tf2x32(K0, K1, 0u, 0u, A0, A1);     // carried key after split #1
    tf2x32(K0, K1, 0u, 1u, s10, s11);   // subkey round 1
    tf2x32(A0, A1, 0u, 1u, s20, s21);   // subkey round 2 (from carried key)

    // round-2 keys: positions of the 4 smallest (bits<<32|pos) keys
    unsigned long long best[4] = {~0ull, ~0ull, ~0ull, ~0ull};
    for (int i = 0; i < NN; ++i) {
      uint32_t r0, r1;
      tf2x32(s20, s21, 0u, (uint32_t)i, r0, r1);
      unsigned long long k = ((unsigned long long)(r0 ^ r1) << 32) | (unsigned)i;
      if (k < best[3]) {
        best[3] = k;
        if (best[3] < best[2]) std::swap(best[3], best[2]);
        if (best[2] < best[1]) std::swap(best[2], best[1]);
        if (best[1] < best[0]) std::swap(best[1], best[0]);
      }
    }
    // round-1 keys: full stable order via (bits<<32|pos) sort
    for (int i = 0; i < NN; ++i) {
      uint32_t r0, r1;
      tf2x32(s10, s11, 0u, (uint32_t)i, r0, r1);
      kbuf[i] = ((unsigned long long)(r0 ^ r1) << 32) | (unsigned)i;
    }
    std::sort(kbuf, kbuf + NN);
    for (int t = 0; t < 4; ++t) {
      int p = (int)(best[t] & 0xFFFFFFFFull);      // target rank
      g_idx_host[s * 4 + t] = (int)(kbuf[p] & 0xFFFFFFFFull);  // perm1[p]
    }
  }
}

extern "C" void kernel_launch(void* const* d_in, const int* in_sizes, int n_in,
                              void* d_out, int out_size, void* d_ws, size_t ws_size,
                              hipStream_t stream) {
  (void)in_sizes; (void)n_in; (void)out_size; (void)ws_size;
  const float2* pred = (const float2*)d_in[0];
  const float2* targ = (const float2*)d_in[1];
  const float2* pos  = (const float2*)d_in[2];
  const float*  obst = (const float*)d_in[3];
  float* ws = (float*)d_ws;
  int* idxbuf = ((int*)d_ws) + WS_IDX;
  float* out = (float*)d_out;

  std::call_once(g_idx_flag, compute_idx_host);

  hipMemcpyAsync(idxbuf, g_idx_host, sizeof(int) * NSAMP * 4,
                 hipMemcpyHostToDevice, stream);
  hipLaunchKernelGGL(k_velbnd, dim3(64), dim3(256), 0, stream, pred, targ, pos, ws);
  hipLaunchKernelGGL(k_cons, dim3(64), dim3(256), 0, stream, pos, pred, ws + WS_CONS);
  hipLaunchKernelGGL(k_obs, dim3(BB * MM), dim3(64), 0, stream, pos, pred, obst, ws);
  hipLaunchKernelGGL(k_final, dim3(1), dim3(256), 0, stream, ws, idxbuf, pos, pred, out);
}

// Round 4
// 42.915 us; speedup vs baseline: 4.7715x; 1.9907x over previous
//
#include <hip/hip_runtime.h>
#include <stdint.h>
#include <algorithm>
#include <mutex>

#define BB 4
#define NN 4096
#define MM 16
#define KNN 5
#define NSAMP 100
#define GL 16          // lanes cooperating per query in k_cons

// workspace float-index layout
#define WS_CONS  0      // 1024 floats: per-block cons partial sums
#define WS_VEL   1024   // 4
#define WS_BSUM  1028   // 4
#define WS_BCNT  1032   // 4
#define WS_OPEN  1036   // 256 (obstacle pen partials: (b,m) x 4 parts)
#define WS_OCNT  1292   // 256
#define WS_IDX   1548   // 400 ints (100 samples x 4 indices)
#define WS_GCELL 1948   // 4*257 = 1028 ints (cellstart per batch)
#define WS_GIDX  2976   // 16384 ints (cell-sorted original indices)
#define WS_GPOS  19360  // 32768 floats (cell-sorted float2), byte-off 77440 (8-aligned)

#define CELLH 0.0625f  // 1/16

// ---------------- threefry2x32 (bit-exact JAX) ----------------
__host__ __device__ __forceinline__ void tf2x32(uint32_t k0, uint32_t k1,
                                                uint32_t c0, uint32_t c1,
                                                uint32_t& o0, uint32_t& o1) {
  const uint32_t ks2 = k0 ^ k1 ^ 0x1BD11BDAu;
  uint32_t x0 = c0 + k0, x1 = c1 + k1;
#define TF_RND(r) { x0 += x1; x1 = (x1 << (r)) | (x1 >> (32 - (r))); x1 ^= x0; }
  TF_RND(13) TF_RND(15) TF_RND(26) TF_RND(6)
  x0 += k1;  x1 += ks2 + 1u;
  TF_RND(17) TF_RND(29) TF_RND(16) TF_RND(24)
  x0 += ks2; x1 += k0 + 2u;
  TF_RND(13) TF_RND(15) TF_RND(26) TF_RND(6)
  x0 += k0;  x1 += k1 + 3u;
  TF_RND(17) TF_RND(29) TF_RND(16) TF_RND(24)
  x0 += k1;  x1 += ks2 + 4u;
  TF_RND(13) TF_RND(15) TF_RND(26) TF_RND(6)
  x0 += ks2; x1 += k0 + 5u;
#undef TF_RND
  o0 = x0; o1 = x1;
}

__device__ __forceinline__ float blockReduce256(float v, float* red) {
  int t = threadIdx.x;
  red[t] = v;
  __syncthreads();
#pragma unroll
  for (int off = 128; off > 0; off >>= 1) {
    if (t < off) red[t] += red[t + off];
    __syncthreads();
  }
  float r = red[0];
  __syncthreads();
  return r;
}

// ---------------- k_pre: per-batch binning + vel-MSE + boundary partials ----
// 4 blocks (one per batch). Bins the batch ONCE into global (cell-sorted
// gpos/gidx + cellstart) and computes the velbnd partial sums in the same
// pass (elementwise math identical to the verified k_velbnd).
__global__ __launch_bounds__(256) void k_pre(const float2* __restrict__ pred,
                                             const float2* __restrict__ targ,
                                             const float2* __restrict__ pos,
                                             float* __restrict__ ws,
                                             float2* __restrict__ gpos,
                                             int* __restrict__ gidx,
                                             int* __restrict__ gcell) {
  __shared__ int ccur[256];
  __shared__ int cellstart[257];
  __shared__ float red[256];
  int b = blockIdx.x;
  int tid = threadIdx.x;

  ccur[tid] = 0;
  __syncthreads();

  float2 mypts[16];
  int mycell[16];
  float velsq = 0.0f, bs = 0.0f, bc = 0.0f;
#pragma unroll
  for (int r = 0; r < 16; ++r) {
    int gi = b * NN + r * 256 + tid;
    float2 p = pos[gi];
    mypts[r] = p;
    int cx = (int)(p.x * 16.0f); cx = cx > 15 ? 15 : cx;
    int cy = (int)(p.y * 16.0f); cy = cy > 15 ? 15 : cy;
    int c = cx * 16 + cy;
    mycell[r] = c;
    atomicAdd(&ccur[c], 1);

    // ---- velbnd elementwise (verbatim) ----
    float2 pr = pred[gi], tg = targ[gi];
    float ex = pr.x - tg.x, ey = pr.y - tg.y;
    velsq += ex * ex + ey * ey;
    float x = p.x, y = p.y;
    bool mask = (x < 0.05f) || (x > 0.95f) || (y < 0.05f) || (y > 0.95f);
    float m0 = x, m1 = 1.0f - x, m2 = y, m3 = 1.0f - y;
    int bt = 0; float mv = m0;
    if (m1 < mv) { mv = m1; bt = 1; }
    if (m2 < mv) { mv = m2; bt = 2; }
    if (m3 < mv) { mv = m3; bt = 3; }
    float nx = (bt == 0) ? -1.0f : (bt == 1 ? 1.0f : 0.0f);
    float ny = (bt == 2) ? -1.0f : (bt == 3 ? 1.0f : 0.0f);
    float nc = pr.x * nx + pr.y * ny;
    bs += mask ? nc * nc : 0.0f;
    bc += mask ? 1.0f : 0.0f;
  }
  __syncthreads();

  // ---- exclusive scan (Hillis-Steele over 257 entries) ----
  if (tid == 0) cellstart[0] = 0;
  cellstart[tid + 1] = ccur[tid];
  __syncthreads();
#pragma unroll
  for (int off = 1; off < 256; off <<= 1) {
    int i = tid + 1;
    int v = (i >= off) ? cellstart[i - off] : 0;
    __syncthreads();
    if (i >= off) cellstart[i] += v;
    __syncthreads();
  }
  gcell[b * 257 + tid] = cellstart[tid];
  if (tid == 0) gcell[b * 257 + 256] = cellstart[256];
  ccur[tid] = cellstart[tid];        // scatter cursors
  __syncthreads();

  // ---- scatter to GLOBAL cell-sorted arrays ----
#pragma unroll
  for (int r = 0; r < 16; ++r) {
    int slot = atomicAdd(&ccur[mycell[r]], 1);
    gpos[b * NN + slot] = mypts[r];
    gidx[b * NN + slot] = r * 256 + tid;
  }

  // ---- velbnd partials ----
  float v1 = blockReduce256(velsq, red);
  float v2 = blockReduce256(bs, red);
  float v3 = blockReduce256(bc, red);
  if (tid == 0) {
    ws[WS_VEL + b] = v1;
    ws[WS_BSUM + b] = v2;
    ws[WS_BCNT + b] = v3;
  }
}

// ---------------- k_cons: exact kNN search, 16 lanes per query ----------------
// 1024 blocks x 256 threads; group of GL=16 lanes per query. Each lane scans a
// GL-strided slice of the clamped 3x3 neighborhood into a private top-5 (key =
// (dist_bits<<32 | j), distance formula verbatim), then a 5-round shfl-min
// merge reproduces the exact global top-5. Conservative bound check as before;
// on failure (prob ~1e-15, or <5 candidates) exact brute-force fallback.
// FIX vs r3: scell[256] was never initialized (tid<256) -> garbage span bound
// -> wild global reads -> abort. Load it explicitly.
__global__ __launch_bounds__(256) void k_cons(const float2* __restrict__ gpos,
                                              const int* __restrict__ gidx,
                                              const int* __restrict__ gcell,
                                              const float2* __restrict__ vel,
                                              float* __restrict__ partial) {
  __shared__ int scell[257];
  __shared__ float red[256];
  int tid = threadIdx.x;
  int batch = blockIdx.x >> 8;                 // 256 blocks per batch
  int q = ((blockIdx.x & 255) << 4) + (tid >> 4);  // sorted index in batch
  int lane = tid & (GL - 1);

  scell[tid] = gcell[batch * 257 + tid];
  if (tid == 0) scell[256] = gcell[batch * 257 + 256];
  __syncthreads();

  const float2* bp = gpos + batch * NN;
  const int* bi = gidx + batch * NN;

  float2 pi = bp[q];
  int iorig = bi[q];
  float sqi = pi.x * pi.x + pi.y * pi.y;
  int cx = (int)(pi.x * 16.0f); cx = cx > 15 ? 15 : cx;
  int cy = (int)(pi.y * 16.0f); cy = cy > 15 ? 15 : cy;

  unsigned long long b0 = ~0ull, b1 = ~0ull, b2 = ~0ull, b3 = ~0ull, b4 = ~0ull;

  auto insert = [&](int s) {
    float2 pj = bp[s];
    int jn = bi[s];
    if (jn == iorig) return;                   // self-exclusion
    float sqj = pj.x * pj.x + pj.y * pj.y;
    float dt = pi.x * pj.x + pi.y * pj.y;
    float d2 = sqi + sqj - 2.0f * dt;          // reference formula, verbatim
    float dist = sqrtf(fmaxf(d2, 0.0f));
    unsigned long long key =
        ((unsigned long long)__float_as_uint(dist) << 32) | (unsigned)jn;
    if (key < b4) {
      b4 = key;
      if (b4 < b3) { unsigned long long t2 = b4; b4 = b3; b3 = t2; }
      if (b3 < b2) { unsigned long long t2 = b3; b3 = b2; b2 = t2; }
      if (b2 < b1) { unsigned long long t2 = b2; b2 = b1; b1 = t2; }
      if (b1 < b0) { unsigned long long t2 = b1; b1 = b0; b0 = t2; }
    }
  };

  // ---- clamped 3x3 neighborhood, lane-strided ----
  int xlo = cx - 1; if (xlo < 0) xlo = 0;
  int xhi = cx + 1; if (xhi > 15) xhi = 15;
  int ylo = cy - 1; if (ylo < 0) ylo = 0;
  int yhi = cy + 1; if (yhi > 15) yhi = 15;
  for (int gx = xlo; gx <= xhi; ++gx) {
    int s0 = scell[(gx << 4) + ylo];
    int s1 = scell[(gx << 4) + yhi + 1];
    for (int s = s0 + lane; s < s1; s += GL) insert(s);
  }

  // ---- merge-pop across the 16-lane group: exact key-ordered top-5 ----
  unsigned long long w0, w1, w2, w3, w4;
#define MERGE_ROUND(W) {                                        \
    unsigned long long m = b0, o;                               \
    o = __shfl_xor(m, 1, GL); m = (o < m) ? o : m;              \
    o = __shfl_xor(m, 2, GL); m = (o < m) ? o : m;              \
    o = __shfl_xor(m, 4, GL); m = (o < m) ? o : m;              \
    o = __shfl_xor(m, 8, GL); m = (o < m) ? o : m;              \
    if (b0 == m) { b0 = b1; b1 = b2; b2 = b3; b3 = b4; b4 = ~0ull; } \
    W = m; }
  MERGE_ROUND(w0) MERGE_ROUND(w1) MERGE_ROUND(w2) MERGE_ROUND(w3) MERGE_ROUND(w4)

  // ---- conservative bound check (group-uniform) ----
  float dist5 = __uint_as_float((uint32_t)(w4 >> 32));  // NaN if <5 found
  float dout = 1e30f;
  if (xlo > 0)  dout = fminf(dout, pi.x - (float)xlo * CELLH);
  if (xhi < 15) dout = fminf(dout, (float)(xhi + 1) * CELLH - pi.x);
  if (ylo > 0)  dout = fminf(dout, pi.y - (float)ylo * CELLH);
  if (yhi < 15) dout = fminf(dout, (float)(yhi + 1) * CELLH - pi.y);
  if (!(dist5 + 1e-3f <= dout)) {
    // exact brute-force fallback over the whole batch (runs ~never)
    b0 = b1 = b2 = b3 = b4 = ~0ull;
    for (int s = lane; s < NN; s += GL) insert(s);
    MERGE_ROUND(w0) MERGE_ROUND(w1) MERGE_ROUND(w2) MERGE_ROUND(w3) MERGE_ROUND(w4)
  }
#undef MERGE_ROUND

  // ---- contribution: lane 0 accumulates the 5 terms SEQUENTIALLY in
  // increasing-key order — identical fp order to the verified r2 kernel ----
  float acc = 0.0f;
  if (lane == 0) {
    float2 vi = vel[batch * NN + iorig];
    unsigned long long wins[5] = {w0, w1, w2, w3, w4};
#pragma unroll
    for (int kk = 0; kk < KNN; ++kk) {
      unsigned long long m = wins[kk];
      unsigned jn = (unsigned)(m & 0xFFFFFFFFull);
      float dn = __uint_as_float((uint32_t)(m >> 32));
      float2 vj = vel[batch * NN + jn];
      float dvx = vi.x - vj.x, dvy = vi.y - vj.y;
      float vd = sqrtf(dvx * dvx + dvy * dvy);
      float w = 1.0f / (dn + 1e-6f);
      acc += vd * w;
    }
  }
  float tot = blockReduce256(acc, red);
  if (tid == 0) partial[blockIdx.x] = tot;
}

// ---------------- obstacle loss: 256 blocks, (b,m) x 4 parts ----------------
__global__ __launch_bounds__(256) void k_obs(const float2* __restrict__ pos,
                                             const float2* __restrict__ vel,
                                             const float* __restrict__ obst,
                                             float* __restrict__ ws) {
  __shared__ float red[256];
  int blk = blockIdx.x;        // bm*4 + part
  int bm = blk >> 2, part = blk & 3;
  int b = bm >> 4;
  int tid = threadIdx.x;
  float cx = obst[bm * 3 + 0], cy = obst[bm * 3 + 1], r = obst[bm * 3 + 2];
  float pensum = 0.0f, cnt = 0.0f;
#pragma unroll
  for (int it = 0; it < 4; ++it) {
    int n = part * 1024 + it * 256 + tid;
    float2 ps = pos[b * NN + n];
    float2 v = vel[b * NN + n];
    float dx = ps.x - cx, dy = ps.y - cy;
    float d = sqrtf(dx * dx + dy * dy);
    bool near = d < r * 2.0f;
    float dpe = d + 1e-6f;
    float dirx = dx / dpe, diry = dy / dpe;
    float w = expf(-(d - r) / (r * 0.5f));
    float proj = v.x * dirx + v.y * diry;
    float npj = fmaxf(-proj, 0.0f);
    float pp = w * npj * npj;
    if (near) { pensum += pp; cnt += 1.0f; }
  }
  float ps2 = blockReduce256(pensum, red);
  float cs2 = blockReduce256(cnt, red);
  if (tid == 0) { ws[WS_OPEN + blk] = ps2; ws[WS_OCNT + blk] = cs2; }
}

// ---------------- final combine ----------------
__global__ __launch_bounds__(256) void k_final(const float* __restrict__ ws,
                                               const int* __restrict__ idxbuf,
                                               const float2* __restrict__ pos,
                                               const float2* __restrict__ vel,
                                               float* __restrict__ out) {
  __shared__ float red[256];
  int t = threadIdx.x;
  float acc;

  acc = 0.0f;
  for (int q = t; q < 1024; q += 256) acc += ws[WS_CONS + q];
  float consS = blockReduce256(acc, red);

  acc = (t < 4) ? ws[WS_VEL + t] : 0.0f;
  float velS = blockReduce256(acc, red);

  acc = (t < 4) ? ws[WS_BSUM + t] : 0.0f;
  float bsumS = blockReduce256(acc, red);

  acc = (t < 4) ? ws[WS_BCNT + t] : 0.0f;
  float bcntS = blockReduce256(acc, red);

  acc = 0.0f;
  if (t < 64) {
    float psum = 0.0f, c = 0.0f;
#pragma unroll
    for (int p = 0; p < 4; ++p) {
      psum += ws[WS_OPEN + t * 4 + p];
      c += ws[WS_OCNT + t * 4 + p];
    }
    acc = (c > 0.0f) ? psum / fmaxf(c, 1.0f) : 0.0f;
  }
  float obsS = blockReduce256(acc, red);

  acc = 0.0f;
  for (int q = t; q < BB * NSAMP; q += 256) {
    int b = q / NSAMP, s = q % NSAMP;
    int i0 = idxbuf[s * 4 + 0], i1 = idxbuf[s * 4 + 1], i2 = idxbuf[s * 4 + 2];
    float2 p0 = pos[b * NN + i0], p1 = pos[b * NN + i1], p2 = pos[b * NN + i2];
    float2 v0 = vel[b * NN + i0], v1 = vel[b * NN + i1], v2 = vel[b * NN + i2];
    float dx = p1.x - p0.x, dy = p2.y - p0.y;
    float dvx = (v1.x - v0.x) / (dx + 1e-6f);
    float dvy = (v2.y - v0.y) / (dy + 1e-6f);
    float sm = dvx + dvy;
    acc += sm * sm;
  }
  float divS = blockReduce256(acc, red);

  if (t == 0) {
    float vel_loss = velS / (float)(BB * NN * 2);
    float cons = consS / (float)(BB * NN * KNN);
    float bnd = (bcntS > 0.0f) ? bsumS / fmaxf(bcntS, 1.0f) : 0.0f;
    float obs = obsS / (float)(BB * MM);
    float dv = divS / (float)(BB * NSAMP);
    out[0] = 1.0f * vel_loss + 0.1f * cons + 0.5f * bnd + 1.0f * obs + 0.1f * dv;
  }
}

// ---------------- host-side JAX permutation indices ----------------
static int  g_idx_host[NSAMP * 4];
static std::once_flag g_idx_flag;

static void compute_idx_host() {
  static unsigned long long kbuf[NN];
  for (int s = 0; s < NSAMP; ++s) {
    uint32_t K0, K1;                    // keys[s] = tf(base, (0, s))
    tf2x32(0u, 42u, 0u, (uint32_t)s, K0, K1);
    uint32_t A0, A1, s10, s11, s20, s21;
    tf2x32(K0, K1, 0u, 0u, A0, A1);     // carried key after split #1
    tf2x32(K0, K1, 0u, 1u, s10, s11);   // subkey round 1
    tf2x32(A0, A1, 0u, 1u, s20, s21);   // subkey round 2 (from carried key)

    unsigned long long best[4] = {~0ull, ~0ull, ~0ull, ~0ull};
    for (int i = 0; i < NN; ++i) {
      uint32_t r0, r1;
      tf2x32(s20, s21, 0u, (uint32_t)i, r0, r1);
      unsigned long long k = ((unsigned long long)(r0 ^ r1) << 32) | (unsigned)i;
      if (k < best[3]) {
        best[3] = k;
        if (best[3] < best[2]) std::swap(best[3], best[2]);
        if (best[2] < best[1]) std::swap(best[2], best[1]);
        if (best[1] < best[0]) std::swap(best[1], best[0]);
      }
    }
    for (int i = 0; i < NN; ++i) {
      uint32_t r0, r1;
      tf2x32(s10, s11, 0u, (uint32_t)i, r0, r1);
      kbuf[i] = ((unsigned long long)(r0 ^ r1) << 32) | (unsigned)i;
    }
    std::sort(kbuf, kbuf + NN);
    for (int t = 0; t < 4; ++t) {
      int p = (int)(best[t] & 0xFFFFFFFFull);
      g_idx_host[s * 4 + t] = (int)(kbuf[p] & 0xFFFFFFFFull);
    }
  }
}

extern "C" void kernel_launch(void* const* d_in, const int* in_sizes, int n_in,
                              void* d_out, int out_size, void* d_ws, size_t ws_size,
                              hipStream_t stream) {
  (void)in_sizes; (void)n_in; (void)out_size; (void)ws_size;
  const float2* pred = (const float2*)d_in[0];
  const float2* targ = (const float2*)d_in[1];
  const float2* pos  = (const float2*)d_in[2];
  const float*  obst = (const float*)d_in[3];
  float* ws = (float*)d_ws;
  int* idxbuf = ((int*)d_ws) + WS_IDX;
  int* gcell  = ((int*)d_ws) + WS_GCELL;
  int* gidx   = ((int*)d_ws) + WS_GIDX;
  float2* gpos = (float2*)(((float*)d_ws) + WS_GPOS);
  float* out = (float*)d_out;

  std::call_once(g_idx_flag, compute_idx_host);

  hipMemcpyAsync(idxbuf, g_idx_host, sizeof(int) * NSAMP * 4,
                 hipMemcpyHostToDevice, stream);
  hipLaunchKernelGGL(k_pre, dim3(BB), dim3(256), 0, stream,
                     pred, targ, pos, ws, gpos, gidx, gcell);
  hipLaunchKernelGGL(k_obs, dim3(256), dim3(256), 0, stream, pos, pred, obst, ws);
  hipLaunchKernelGGL(k_cons, dim3(1024), dim3(256), 0, stream,
                     gpos, gidx, gcell, pred, ws + WS_CONS);
  hipLaunchKernelGGL(k_final, dim3(1), dim3(256), 0, stream, ws, idxbuf, pos, pred, out);
}

// Round 5
// 40.095 us; speedup vs baseline: 5.1071x; 1.0703x over previous
//
#include <hip/hip_runtime.h>
#include <stdint.h>
#include <algorithm>
#include <mutex>

#define BB 4
#define NN 4096
#define MM 16
#define KNN 5
#define NSAMP 100
#define GL 16          // lanes cooperating per query in k_cons

// workspace float-index layout
#define WS_CONS  0      // 1024 floats: per-block cons partial sums
#define WS_VEL   1024   // 4
#define WS_BSUM  1028   // 4
#define WS_BCNT  1032   // 4
#define WS_OPEN  1036   // 256 (obstacle pen partials: (b,m) x 4 parts)
#define WS_OCNT  1292   // 256
#define WS_IDX   1548   // 400 ints (100 samples x 4 indices)
#define WS_GCELL 1948   // 4*257 = 1028 ints (cellstart per batch)
#define WS_GIDX  2976   // 16384 ints (cell-sorted original indices)
#define WS_GPOS  19360  // 32768 floats (cell-sorted float2), byte-off 77440 (8-aligned)

#define CELLH 0.0625f  // 1/16

// ---------------- threefry2x32 (bit-exact JAX) ----------------
__host__ __device__ __forceinline__ void tf2x32(uint32_t k0, uint32_t k1,
                                                uint32_t c0, uint32_t c1,
                                                uint32_t& o0, uint32_t& o1) {
  const uint32_t ks2 = k0 ^ k1 ^ 0x1BD11BDAu;
  uint32_t x0 = c0 + k0, x1 = c1 + k1;
#define TF_RND(r) { x0 += x1; x1 = (x1 << (r)) | (x1 >> (32 - (r))); x1 ^= x0; }
  TF_RND(13) TF_RND(15) TF_RND(26) TF_RND(6)
  x0 += k1;  x1 += ks2 + 1u;
  TF_RND(17) TF_RND(29) TF_RND(16) TF_RND(24)
  x0 += ks2; x1 += k0 + 2u;
  TF_RND(13) TF_RND(15) TF_RND(26) TF_RND(6)
  x0 += k0;  x1 += k1 + 3u;
  TF_RND(17) TF_RND(29) TF_RND(16) TF_RND(24)
  x0 += k1;  x1 += ks2 + 4u;
  TF_RND(13) TF_RND(15) TF_RND(26) TF_RND(6)
  x0 += ks2; x1 += k0 + 5u;
#undef TF_RND
  o0 = x0; o1 = x1;
}

__device__ __forceinline__ float blockReduce256(float v, float* red) {
  int t = threadIdx.x;
  red[t] = v;
  __syncthreads();
#pragma unroll
  for (int off = 128; off > 0; off >>= 1) {
    if (t < off) red[t] += red[t + off];
    __syncthreads();
  }
  float r = red[0];
  __syncthreads();
  return r;
}

// ---------------- k_pre: per-batch binning + vel-MSE + boundary partials ----
// 4 blocks (one per batch). Bins the batch ONCE into global (cell-sorted
// gpos/gidx + cellstart) and computes the velbnd partial sums in the same
// pass (elementwise math identical to the verified k_velbnd).
__global__ __launch_bounds__(256) void k_pre(const float2* __restrict__ pred,
                                             const float2* __restrict__ targ,
                                             const float2* __restrict__ pos,
                                             float* __restrict__ ws,
                                             float2* __restrict__ gpos,
                                             int* __restrict__ gidx,
                                             int* __restrict__ gcell) {
  __shared__ int ccur[256];
  __shared__ int cellstart[257];
  __shared__ float red[256];
  int b = blockIdx.x;
  int tid = threadIdx.x;

  ccur[tid] = 0;
  __syncthreads();

  float2 mypts[16];
  int mycell[16];
  float velsq = 0.0f, bs = 0.0f, bc = 0.0f;
#pragma unroll
  for (int r = 0; r < 16; ++r) {
    int gi = b * NN + r * 256 + tid;
    float2 p = pos[gi];
    mypts[r] = p;
    int cx = (int)(p.x * 16.0f); cx = cx > 15 ? 15 : cx;
    int cy = (int)(p.y * 16.0f); cy = cy > 15 ? 15 : cy;
    int c = cx * 16 + cy;
    mycell[r] = c;
    atomicAdd(&ccur[c], 1);

    // ---- velbnd elementwise (verbatim) ----
    float2 pr = pred[gi], tg = targ[gi];
    float ex = pr.x - tg.x, ey = pr.y - tg.y;
    velsq += ex * ex + ey * ey;
    float x = p.x, y = p.y;
    bool mask = (x < 0.05f) || (x > 0.95f) || (y < 0.05f) || (y > 0.95f);
    float m0 = x, m1 = 1.0f - x, m2 = y, m3 = 1.0f - y;
    int bt = 0; float mv = m0;
    if (m1 < mv) { mv = m1; bt = 1; }
    if (m2 < mv) { mv = m2; bt = 2; }
    if (m3 < mv) { mv = m3; bt = 3; }
    float nx = (bt == 0) ? -1.0f : (bt == 1 ? 1.0f : 0.0f);
    float ny = (bt == 2) ? -1.0f : (bt == 3 ? 1.0f : 0.0f);
    float nc = pr.x * nx + pr.y * ny;
    bs += mask ? nc * nc : 0.0f;
    bc += mask ? 1.0f : 0.0f;
  }
  __syncthreads();

  // ---- exclusive scan (Hillis-Steele over 257 entries) ----
  if (tid == 0) cellstart[0] = 0;
  cellstart[tid + 1] = ccur[tid];
  __syncthreads();
#pragma unroll
  for (int off = 1; off < 256; off <<= 1) {
    int i = tid + 1;
    int v = (i >= off) ? cellstart[i - off] : 0;
    __syncthreads();
    if (i >= off) cellstart[i] += v;
    __syncthreads();
  }
  gcell[b * 257 + tid] = cellstart[tid];
  if (tid == 0) gcell[b * 257 + 256] = cellstart[256];
  ccur[tid] = cellstart[tid];        // scatter cursors
  __syncthreads();

  // ---- scatter to GLOBAL cell-sorted arrays ----
#pragma unroll
  for (int r = 0; r < 16; ++r) {
    int slot = atomicAdd(&ccur[mycell[r]], 1);
    gpos[b * NN + slot] = mypts[r];
    gidx[b * NN + slot] = r * 256 + tid;
  }

  // ---- velbnd partials ----
  float v1 = blockReduce256(velsq, red);
  float v2 = blockReduce256(bs, red);
  float v3 = blockReduce256(bc, red);
  if (tid == 0) {
    ws[WS_VEL + b] = v1;
    ws[WS_BSUM + b] = v2;
    ws[WS_BCNT + b] = v3;
  }
}

// ---------------- k_cons: exact kNN search + fused obstacle loss ----------------
// Blocks [0,1024): kNN consistency search, 16 lanes per query (verbatim r4 math).
// Blocks [1024,1280): obstacle loss body (verbatim r4 k_obs math) — fused here
// to drop one graph node; writes disjoint ws regions.
__global__ __launch_bounds__(256) void k_cons(const float2* __restrict__ gpos,
                                              const int* __restrict__ gidx,
                                              const int* __restrict__ gcell,
                                              const float2* __restrict__ vel,
                                              const float2* __restrict__ pos,
                                              const float* __restrict__ obst,
                                              float* __restrict__ ws) {
  __shared__ int scell[257];
  __shared__ float red[256];
  int tid = threadIdx.x;

  if (blockIdx.x >= 1024) {
    // ---------- obstacle part: (b,m) x 4 parts ----------
    int blk = blockIdx.x - 1024;     // bm*4 + part
    int bm = blk >> 2, part = blk & 3;
    int b = bm >> 4;
    float cx = obst[bm * 3 + 0], cy = obst[bm * 3 + 1], r = obst[bm * 3 + 2];
    float pensum = 0.0f, cnt = 0.0f;
#pragma unroll
    for (int it = 0; it < 4; ++it) {
      int n = part * 1024 + it * 256 + tid;
      float2 ps = pos[b * NN + n];
      float2 v = vel[b * NN + n];
      float dx = ps.x - cx, dy = ps.y - cy;
      float d = sqrtf(dx * dx + dy * dy);
      bool near = d < r * 2.0f;
      float dpe = d + 1e-6f;
      float dirx = dx / dpe, diry = dy / dpe;
      float w = expf(-(d - r) / (r * 0.5f));
      float proj = v.x * dirx + v.y * diry;
      float npj = fmaxf(-proj, 0.0f);
      float pp = w * npj * npj;
      if (near) { pensum += pp; cnt += 1.0f; }
    }
    float ps2 = blockReduce256(pensum, red);
    float cs2 = blockReduce256(cnt, red);
    if (tid == 0) { ws[WS_OPEN + blk] = ps2; ws[WS_OCNT + blk] = cs2; }
    return;
  }

  // ---------- consistency part ----------
  int batch = blockIdx.x >> 8;                 // 256 blocks per batch
  int q = ((blockIdx.x & 255) << 4) + (tid >> 4);  // sorted index in batch
  int lane = tid & (GL - 1);

  scell[tid] = gcell[batch * 257 + tid];
  if (tid == 0) scell[256] = gcell[batch * 257 + 256];
  __syncthreads();

  const float2* bp = gpos + batch * NN;
  const int* bi = gidx + batch * NN;

  float2 pi = bp[q];
  int iorig = bi[q];
  float sqi = pi.x * pi.x + pi.y * pi.y;
  int cx = (int)(pi.x * 16.0f); cx = cx > 15 ? 15 : cx;
  int cy = (int)(pi.y * 16.0f); cy = cy > 15 ? 15 : cy;

  unsigned long long b0 = ~0ull, b1 = ~0ull, b2 = ~0ull, b3 = ~0ull, b4 = ~0ull;

  auto insert = [&](int s) {
    float2 pj = bp[s];
    int jn = bi[s];
    if (jn == iorig) return;                   // self-exclusion
    float sqj = pj.x * pj.x + pj.y * pj.y;
    float dt = pi.x * pj.x + pi.y * pj.y;
    float d2 = sqi + sqj - 2.0f * dt;          // reference formula, verbatim
    float dist = sqrtf(fmaxf(d2, 0.0f));
    unsigned long long key =
        ((unsigned long long)__float_as_uint(dist) << 32) | (unsigned)jn;
    if (key < b4) {
      b4 = key;
      if (b4 < b3) { unsigned long long t2 = b4; b4 = b3; b3 = t2; }
      if (b3 < b2) { unsigned long long t2 = b3; b3 = b2; b2 = t2; }
      if (b2 < b1) { unsigned long long t2 = b2; b2 = b1; b1 = t2; }
      if (b1 < b0) { unsigned long long t2 = b1; b1 = b0; b0 = t2; }
    }
  };

  // ---- clamped 3x3 neighborhood, lane-strided ----
  int xlo = cx - 1; if (xlo < 0) xlo = 0;
  int xhi = cx + 1; if (xhi > 15) xhi = 15;
  int ylo = cy - 1; if (ylo < 0) ylo = 0;
  int yhi = cy + 1; if (yhi > 15) yhi = 15;
  for (int gx = xlo; gx <= xhi; ++gx) {
    int s0 = scell[(gx << 4) + ylo];
    int s1 = scell[(gx << 4) + yhi + 1];
    for (int s = s0 + lane; s < s1; s += GL) insert(s);
  }

  // ---- merge-pop across the 16-lane group: exact key-ordered top-5 ----
  unsigned long long w0, w1, w2, w3, w4;
#define MERGE_ROUND(W) {                                        \
    unsigned long long m = b0, o;                               \
    o = __shfl_xor(m, 1, GL); m = (o < m) ? o : m;              \
    o = __shfl_xor(m, 2, GL); m = (o < m) ? o : m;              \
    o = __shfl_xor(m, 4, GL); m = (o < m) ? o : m;              \
    o = __shfl_xor(m, 8, GL); m = (o < m) ? o : m;              \
    if (b0 == m) { b0 = b1; b1 = b2; b2 = b3; b3 = b4; b4 = ~0ull; } \
    W = m; }
  MERGE_ROUND(w0) MERGE_ROUND(w1) MERGE_ROUND(w2) MERGE_ROUND(w3) MERGE_ROUND(w4)

  // ---- conservative bound check (group-uniform) ----
  float dist5 = __uint_as_float((uint32_t)(w4 >> 32));  // NaN if <5 found
  float dout = 1e30f;
  if (xlo > 0)  dout = fminf(dout, pi.x - (float)xlo * CELLH);
  if (xhi < 15) dout = fminf(dout, (float)(xhi + 1) * CELLH - pi.x);
  if (ylo > 0)  dout = fminf(dout, pi.y - (float)ylo * CELLH);
  if (yhi < 15) dout = fminf(dout, (float)(yhi + 1) * CELLH - pi.y);
  if (!(dist5 + 1e-3f <= dout)) {
    // exact brute-force fallback over the whole batch (runs ~never)
    b0 = b1 = b2 = b3 = b4 = ~0ull;
    for (int s = lane; s < NN; s += GL) insert(s);
    MERGE_ROUND(w0) MERGE_ROUND(w1) MERGE_ROUND(w2) MERGE_ROUND(w3) MERGE_ROUND(w4)
  }
#undef MERGE_ROUND

  // ---- contribution: lane 0 accumulates the 5 terms SEQUENTIALLY in
  // increasing-key order — identical fp order to the verified r2 kernel ----
  float acc = 0.0f;
  if (lane == 0) {
    float2 vi = vel[batch * NN + iorig];
    unsigned long long wins[5] = {w0, w1, w2, w3, w4};
#pragma unroll
    for (int kk = 0; kk < KNN; ++kk) {
      unsigned long long m = wins[kk];
      unsigned jn = (unsigned)(m & 0xFFFFFFFFull);
      float dn = __uint_as_float((uint32_t)(m >> 32));
      float2 vj = vel[batch * NN + jn];
      float dvx = vi.x - vj.x, dvy = vi.y - vj.y;
      float vd = sqrtf(dvx * dvx + dvy * dvy);
      float w = 1.0f / (dn + 1e-6f);
      acc += vd * w;
    }
  }
  float tot = blockReduce256(acc, red);
  if (tid == 0) ws[WS_CONS + blockIdx.x] = tot;
}

// ---------------- final combine ----------------
__global__ __launch_bounds__(256) void k_final(const float* __restrict__ ws,
                                               const int* __restrict__ idxbuf,
                                               const float2* __restrict__ pos,
                                               const float2* __restrict__ vel,
                                               float* __restrict__ out) {
  __shared__ float red[256];
  int t = threadIdx.x;
  float acc;

  acc = 0.0f;
  for (int q = t; q < 1024; q += 256) acc += ws[WS_CONS + q];
  float consS = blockReduce256(acc, red);

  acc = (t < 4) ? ws[WS_VEL + t] : 0.0f;
  float velS = blockReduce256(acc, red);

  acc = (t < 4) ? ws[WS_BSUM + t] : 0.0f;
  float bsumS = blockReduce256(acc, red);

  acc = (t < 4) ? ws[WS_BCNT + t] : 0.0f;
  float bcntS = blockReduce256(acc, red);

  acc = 0.0f;
  if (t < 64) {
    float psum = 0.0f, c = 0.0f;
#pragma unroll
    for (int p = 0; p < 4; ++p) {
      psum += ws[WS_OPEN + t * 4 + p];
      c += ws[WS_OCNT + t * 4 + p];
    }
    acc = (c > 0.0f) ? psum / fmaxf(c, 1.0f) : 0.0f;
  }
  float obsS = blockReduce256(acc, red);

  acc = 0.0f;
  for (int q = t; q < BB * NSAMP; q += 256) {
    int b = q / NSAMP, s = q % NSAMP;
    int i0 = idxbuf[s * 4 + 0], i1 = idxbuf[s * 4 + 1], i2 = idxbuf[s * 4 + 2];
    float2 p0 = pos[b * NN + i0], p1 = pos[b * NN + i1], p2 = pos[b * NN + i2];
    float2 v0 = vel[b * NN + i0], v1 = vel[b * NN + i1], v2 = vel[b * NN + i2];
    float dx = p1.x - p0.x, dy = p2.y - p0.y;
    float dvx = (v1.x - v0.x) / (dx + 1e-6f);
    float dvy = (v2.y - v0.y) / (dy + 1e-6f);
    float sm = dvx + dvy;
    acc += sm * sm;
  }
  float divS = blockReduce256(acc, red);

  if (t == 0) {
    float vel_loss = velS / (float)(BB * NN * 2);
    float cons = consS / (float)(BB * NN * KNN);
    float bnd = (bcntS > 0.0f) ? bsumS / fmaxf(bcntS, 1.0f) : 0.0f;
    float obs = obsS / (float)(BB * MM);
    float dv = divS / (float)(BB * NSAMP);
    out[0] = 1.0f * vel_loss + 0.1f * cons + 0.5f * bnd + 1.0f * obs + 0.1f * dv;
  }
}

// ---------------- host-side JAX permutation indices ----------------
static int  g_idx_host[NSAMP * 4];
static std::once_flag g_idx_flag;

static void compute_idx_host() {
  static unsigned long long kbuf[NN];
  for (int s = 0; s < NSAMP; ++s) {
    uint32_t K0, K1;                    // keys[s] = tf(base, (0, s))
    tf2x32(0u, 42u, 0u, (uint32_t)s, K0, K1);
    uint32_t A0, A1, s10, s11, s20, s21;
    tf2x32(K0, K1, 0u, 0u, A0, A1);     // carried key after split #1
    tf2x32(K0, K1, 0u, 1u, s10, s11);   // subkey round 1
    tf2x32(A0, A1, 0u, 1u, s20, s21);   // subkey round 2 (from carried key)

    unsigned long long best[4] = {~0ull, ~0ull, ~0ull, ~0ull};
    for (int i = 0; i < NN; ++i) {
      uint32_t r0, r1;
      tf2x32(s20, s21, 0u, (uint32_t)i, r0, r1);
      unsigned long long k = ((unsigned long long)(r0 ^ r1) << 32) | (unsigned)i;
      if (k < best[3]) {
        best[3] = k;
        if (best[3] < best[2]) std::swap(best[3], best[2]);
        if (best[2] < best[1]) std::swap(best[2], best[1]);
        if (best[1] < best[0]) std::swap(best[1], best[0]);
      }
    }
    for (int i = 0; i < NN; ++i) {
      uint32_t r0, r1;
      tf2x32(s10, s11, 0u, (uint32_t)i, r0, r1);
      kbuf[i] = ((unsigned long long)(r0 ^ r1) << 32) | (unsigned)i;
    }
    std::sort(kbuf, kbuf + NN);
    for (int t = 0; t < 4; ++t) {
      int p = (int)(best[t] & 0xFFFFFFFFull);
      g_idx_host[s * 4 + t] = (int)(kbuf[p] & 0xFFFFFFFFull);
    }
  }
}

extern "C" void kernel_launch(void* const* d_in, const int* in_sizes, int n_in,
                              void* d_out, int out_size, void* d_ws, size_t ws_size,
                              hipStream_t stream) {
  (void)in_sizes; (void)n_in; (void)out_size; (void)ws_size;
  const float2* pred = (const float2*)d_in[0];
  const float2* targ = (const float2*)d_in[1];
  const float2* pos  = (const float2*)d_in[2];
  const float*  obst = (const float*)d_in[3];
  float* ws = (float*)d_ws;
  int* idxbuf = ((int*)d_ws) + WS_IDX;
  int* gcell  = ((int*)d_ws) + WS_GCELL;
  int* gidx   = ((int*)d_ws) + WS_GIDX;
  float2* gpos = (float2*)(((float*)d_ws) + WS_GPOS);
  float* out = (float*)d_out;

  std::call_once(g_idx_flag, compute_idx_host);

  hipMemcpyAsync(idxbuf, g_idx_host, sizeof(int) * NSAMP * 4,
                 hipMemcpyHostToDevice, stream);
  hipLaunchKernelGGL(k_pre, dim3(BB), dim3(256), 0, stream,
                     pred, targ, pos, ws, gpos, gidx, gcell);
  hipLaunchKernelGGL(k_cons, dim3(1280), dim3(256), 0, stream,
                     gpos, gidx, gcell, pred, pos, obst, ws);
  hipLaunchKernelGGL(k_final, dim3(1), dim3(256), 0, stream, ws, idxbuf, pos, pred, out);
}